// Round 4
// baseline (2822.018 us; speedup 1.0000x reference)
//
#include <hip/hip_runtime.h>
#include <hip/hip_bf16.h>
#include <math.h>
#include <stdint.h>

#define NN 50000
#define EE 600000

// ws layout in floats (regions reused across phases; total ~104 MB)
#define Q_OFF    0              // [N,128] Q ; later hmid [N,256] (Q+K)
#define K_OFF    6400000        // [N,128] K
#define V_OFF    12800000       // [N,128] V ; later hfin [N,128]
#define WV_OFF   19200000       // [N,128] wV accum ; attn_bn1 rewrites in-place as h
#define Z_OFF    25600000       // [N,8]
#define ST_OFF   26000000       // 1024: sum1 sq1 sum2 sq2 | a1 bb1 a2 bb2
#define FLAG_OFF 26001024       // 1 int: edge_index dtype flag
#define H_OFF    WV_OFF         // h = x + attn (in-place over wV)
#define HMID_OFF 0              // [N,256] reuses Q+K after edge phase
#define HFIN_OFF 12800000       // [N,128] reuses V

// ------------------------------------------------ edge_index dtype detection
// int64 little-endian with values < 2^31 => every odd 32-bit word is 0.
__global__ void detect_eidx(const int* __restrict__ e32, float* __restrict__ ws) {
  __shared__ int nz;
  if (threadIdx.x == 0) nz = 0;
  __syncthreads();
  if (e32[threadIdx.x * 2 + 1] != 0) atomicAdd(&nz, 1);
  __syncthreads();
  if (threadIdx.x == 0) ((int*)(ws + FLAG_OFF))[0] = (nz == 0) ? 1 : 0;
}

// ---------------------------------------------------------------- proj Q,K,V
__global__ __launch_bounds__(256)
void proj_qkv(const float* __restrict__ x, const float* __restrict__ Wq,
              const float* __restrict__ Wk, const float* __restrict__ Wv,
              float* __restrict__ ws) {
  __shared__ float As[32][68];
  __shared__ float Bs[32][128];
  const int tid = threadIdx.x;
  const int tx = tid & 15, ty = tid >> 4;
  const int row0 = blockIdx.x * 64;
  const float* W = (blockIdx.y == 0) ? Wq : ((blockIdx.y == 1) ? Wk : Wv);
  float* out = ws + ((blockIdx.y == 0) ? Q_OFF : ((blockIdx.y == 1) ? K_OFF : V_OFF));

  float acc[4][8];
#pragma unroll
  for (int i = 0; i < 4; ++i)
#pragma unroll
    for (int j = 0; j < 8; ++j) acc[i][j] = 0.f;

  for (int k0 = 0; k0 < 128; k0 += 32) {
#pragma unroll
    for (int j = 0; j < 2; ++j) {          // A: 64x32
      int s = tid + 256 * j;
      int r = s >> 3, kg = (s & 7) << 2;
      int gr = row0 + r;
      float4 v = make_float4(0.f, 0.f, 0.f, 0.f);
      if (gr < NN) v = *(const float4*)&x[(size_t)gr * 128 + k0 + kg];
      As[kg + 0][r] = v.x; As[kg + 1][r] = v.y; As[kg + 2][r] = v.z; As[kg + 3][r] = v.w;
    }
#pragma unroll
    for (int j = 0; j < 4; ++j) {          // B: 32x128
      int s = tid + 256 * j;
      int kk = s >> 5, cg = (s & 31) << 2;
      *(float4*)&Bs[kk][cg] = *(const float4*)&W[(size_t)(k0 + kk) * 128 + cg];
    }
    __syncthreads();
#pragma unroll
    for (int k = 0; k < 32; ++k) {
      float4 a4 = *(float4*)&As[k][ty << 2];
      float4 b4a = *(float4*)&Bs[k][tx << 3];
      float4 b4b = *(float4*)&Bs[k][(tx << 3) + 4];
      float av[4] = {a4.x, a4.y, a4.z, a4.w};
      float bv[8] = {b4a.x, b4a.y, b4a.z, b4a.w, b4b.x, b4b.y, b4b.z, b4b.w};
#pragma unroll
      for (int i = 0; i < 4; ++i)
#pragma unroll
        for (int j = 0; j < 8; ++j) acc[i][j] = fmaf(av[i], bv[j], acc[i][j]);
    }
    __syncthreads();
  }
#pragma unroll
  for (int i = 0; i < 4; ++i) {
    int gr = row0 + (ty << 2) + i;
    if (gr < NN) {
      float4 o0 = make_float4(acc[i][0], acc[i][1], acc[i][2], acc[i][3]);
      float4 o1 = make_float4(acc[i][4], acc[i][5], acc[i][6], acc[i][7]);
      *(float4*)&out[(size_t)gr * 128 + (tx << 3)] = o0;
      *(float4*)&out[(size_t)gr * 128 + (tx << 3) + 4] = o1;
    }
  }
}

// --------------------------------- edge: E_e GEMM + score + atomic scatter
__global__ __launch_bounds__(256)
void edge_kernel(const float* __restrict__ edge_attr, const void* __restrict__ eidx,
                 const float* __restrict__ We, float* __restrict__ ws) {
  __shared__ float As[32][68];
  __shared__ float Bs[32][128];
  __shared__ int s_src[64], s_dst[64];
  __shared__ int s_is64;
  const int tid = threadIdx.x;
  const int tx = tid & 15, ty = tid >> 4;
  const int e0 = blockIdx.x * 64;   // E = 9375*64 exactly

  if (tid == 0) s_is64 = ((const int*)(ws + FLAG_OFF))[0];
  __syncthreads();
  if (tid < 128) {
    int lane = tid & 63;
    size_t off = (tid < 64) ? (size_t)(e0 + lane) : ((size_t)EE + e0 + lane);
    int idx = s_is64 ? (int)((const long long*)eidx)[off]
                     : ((const int*)eidx)[off];
    if (tid < 64) s_src[lane] = idx; else s_dst[lane] = idx;
  }

  float acc[4][8];
#pragma unroll
  for (int i = 0; i < 4; ++i)
#pragma unroll
    for (int j = 0; j < 8; ++j) acc[i][j] = 0.f;

  for (int k0 = 0; k0 < 128; k0 += 32) {
#pragma unroll
    for (int j = 0; j < 2; ++j) {
      int s = tid + 256 * j;
      int r = s >> 3, kg = (s & 7) << 2;
      float4 v = *(const float4*)&edge_attr[(size_t)(e0 + r) * 128 + k0 + kg];
      As[kg + 0][r] = v.x; As[kg + 1][r] = v.y; As[kg + 2][r] = v.z; As[kg + 3][r] = v.w;
    }
#pragma unroll
    for (int j = 0; j < 4; ++j) {
      int s = tid + 256 * j;
      int kk = s >> 5, cg = (s & 31) << 2;
      *(float4*)&Bs[kk][cg] = *(const float4*)&We[(size_t)(k0 + kk) * 128 + cg];
    }
    __syncthreads();
#pragma unroll
    for (int k = 0; k < 32; ++k) {
      float4 a4 = *(float4*)&As[k][ty << 2];
      float4 b4a = *(float4*)&Bs[k][tx << 3];
      float4 b4b = *(float4*)&Bs[k][(tx << 3) + 4];
      float av[4] = {a4.x, a4.y, a4.z, a4.w};
      float bv[8] = {b4a.x, b4a.y, b4a.z, b4a.w, b4b.x, b4b.y, b4b.z, b4b.w};
#pragma unroll
      for (int i = 0; i < 4; ++i)
#pragma unroll
        for (int j = 0; j < 8; ++j) acc[i][j] = fmaf(av[i], bv[j], acc[i][j]);
    }
    __syncthreads();
  }

  const float* Qm = ws + Q_OFF;
  const float* Km = ws + K_OFF;
  const float* Vm = ws + V_OFF;
  float* wV = ws + WV_OFF;
  float* Z = ws + Z_OFF;
  const int c0 = tx << 3;
  const int hh = tx >> 1;

#pragma unroll
  for (int i = 0; i < 4; ++i) {
    const int src = s_src[(ty << 2) + i];
    const int dst = s_dst[(ty << 2) + i];
    const float* Kp = Km + (size_t)src * 128 + c0;
    const float* Qp = Qm + (size_t)dst * 128 + c0;
    float4 ka = *(const float4*)Kp, kb = *(const float4*)(Kp + 4);
    float4 qa = *(const float4*)Qp, qb = *(const float4*)(Qp + 4);
    float p = acc[i][0] * ka.x * qa.x + acc[i][1] * ka.y * qa.y
            + acc[i][2] * ka.z * qa.z + acc[i][3] * ka.w * qa.w
            + acc[i][4] * kb.x * qb.x + acc[i][5] * kb.y * qb.y
            + acc[i][6] * kb.z * qb.z + acc[i][7] * kb.w * qb.w;
    p *= 0.25f;                         // 1/sqrt(DH)
    p += __shfl_xor(p, 1);              // combine the two half-head partials
    float sc = __expf(fminf(fmaxf(p, -5.f), 5.f));
    if ((tx & 1) == 0) atomicAdd(&Z[(size_t)dst * 8 + hh], sc);
    const float* Vp = Vm + (size_t)src * 128 + c0;
    float4 va = *(const float4*)Vp, vb = *(const float4*)(Vp + 4);
    float* wp = wV + (size_t)dst * 128 + c0;
    atomicAdd(wp + 0, va.x * sc); atomicAdd(wp + 1, va.y * sc);
    atomicAdd(wp + 2, va.z * sc); atomicAdd(wp + 3, va.w * sc);
    atomicAdd(wp + 4, vb.x * sc); atomicAdd(wp + 5, vb.y * sc);
    atomicAdd(wp + 6, vb.z * sc); atomicAdd(wp + 7, vb.w * sc);
  }
}

// ------ h = x + wV/(Z+1e-6) written IN-PLACE over wV; accumulate BN1 stats
__global__ __launch_bounds__(256)
void attn_bn1(const float* __restrict__ x, float* __restrict__ ws) {
  float* wV = ws + WV_OFF;   // read wV, write h to same location
  const float* Z = ws + Z_OFF;
  float* st = ws + ST_OFF;
  const int tid = threadIdx.x;
  const int cg = (tid & 31) << 2;
  const int rl = tid >> 5;
  float s[4] = {0.f, 0.f, 0.f, 0.f}, q[4] = {0.f, 0.f, 0.f, 0.f};
  for (int r = blockIdx.x * 8 + rl; r < NN; r += gridDim.x * 8) {
    float4 xv = *(const float4*)&x[(size_t)r * 128 + cg];
    float4 wv = *(const float4*)&wV[(size_t)r * 128 + cg];
    float zi = 1.f / (Z[(size_t)r * 8 + (cg >> 4)] + 1e-6f);
    float4 hv;
    hv.x = xv.x + wv.x * zi; hv.y = xv.y + wv.y * zi;
    hv.z = xv.z + wv.z * zi; hv.w = xv.w + wv.w * zi;
    *(float4*)&wV[(size_t)r * 128 + cg] = hv;
    s[0] += hv.x; s[1] += hv.y; s[2] += hv.z; s[3] += hv.w;
    q[0] += hv.x * hv.x; q[1] += hv.y * hv.y; q[2] += hv.z * hv.z; q[3] += hv.w * hv.w;
  }
  __shared__ float red[8][32][8];
#pragma unroll
  for (int j = 0; j < 4; ++j) { red[rl][tid & 31][j] = s[j]; red[rl][tid & 31][4 + j] = q[j]; }
  __syncthreads();
  if (tid < 32) {
    float ss[4], qq[4];
#pragma unroll
    for (int j = 0; j < 4; ++j) { ss[j] = red[0][tid][j]; qq[j] = red[0][tid][4 + j]; }
    for (int r2 = 1; r2 < 8; ++r2)
#pragma unroll
      for (int j = 0; j < 4; ++j) { ss[j] += red[r2][tid][j]; qq[j] += red[r2][tid][4 + j]; }
#pragma unroll
    for (int j = 0; j < 4; ++j) {
      atomicAdd(&st[(tid << 2) + j], ss[j]);
      atomicAdd(&st[128 + (tid << 2) + j], qq[j]);
    }
  }
}

// --------------------------- BN finalize: a = g/sqrt(var+eps), b = beta - mu*a
__global__ void bn_finalize(const float* __restrict__ g, const float* __restrict__ beta,
                            float* __restrict__ ws, int sum_off, int out_off) {
  float* st = ws + ST_OFF;
  int c = threadIdx.x;
  float mu = st[sum_off + c] / (float)NN;
  float var = st[sum_off + 128 + c] / (float)NN - mu * mu;
  float istd = 1.f / sqrtf(var + 1e-5f);
  float a = g[c] * istd;
  st[out_off + c] = a;
  st[out_off + 128 + c] = beta[c] - mu * a;
}

// --------------------------- FFN1: hmid = relu(affine1(h) @ W1 + b1)
__global__ __launch_bounds__(256)
void ffn1(const float* __restrict__ W1, const float* __restrict__ b1, float* __restrict__ ws) {
  __shared__ float As[32][68];
  __shared__ float Bs[32][128];
  const float* h = ws + H_OFF;
  const float* a1 = ws + ST_OFF + 512;
  const float* bb1 = ws + ST_OFF + 640;
  float* hmid = ws + HMID_OFF;
  const int tid = threadIdx.x;
  const int tx = tid & 15, ty = tid >> 4;
  const int row0 = blockIdx.x * 64;
  const int c0 = blockIdx.y * 128;

  float acc[4][8];
#pragma unroll
  for (int i = 0; i < 4; ++i)
#pragma unroll
    for (int j = 0; j < 8; ++j) acc[i][j] = 0.f;

  for (int k0 = 0; k0 < 128; k0 += 32) {
#pragma unroll
    for (int j = 0; j < 2; ++j) {
      int s = tid + 256 * j;
      int r = s >> 3, kg = (s & 7) << 2;
      int gr = row0 + r;
      float4 v = make_float4(0.f, 0.f, 0.f, 0.f);
      if (gr < NN) {
        v = *(const float4*)&h[(size_t)gr * 128 + k0 + kg];
        float4 aa = *(const float4*)&a1[k0 + kg];
        float4 bb = *(const float4*)&bb1[k0 + kg];
        v.x = v.x * aa.x + bb.x; v.y = v.y * aa.y + bb.y;
        v.z = v.z * aa.z + bb.z; v.w = v.w * aa.w + bb.w;
      }
      As[kg + 0][r] = v.x; As[kg + 1][r] = v.y; As[kg + 2][r] = v.z; As[kg + 3][r] = v.w;
    }
#pragma unroll
    for (int j = 0; j < 4; ++j) {
      int s = tid + 256 * j;
      int kk = s >> 5, cg = (s & 31) << 2;
      *(float4*)&Bs[kk][cg] = *(const float4*)&W1[(size_t)(k0 + kk) * 256 + c0 + cg];
    }
    __syncthreads();
#pragma unroll
    for (int k = 0; k < 32; ++k) {
      float4 a4 = *(float4*)&As[k][ty << 2];
      float4 b4a = *(float4*)&Bs[k][tx << 3];
      float4 b4b = *(float4*)&Bs[k][(tx << 3) + 4];
      float av[4] = {a4.x, a4.y, a4.z, a4.w};
      float bv[8] = {b4a.x, b4a.y, b4a.z, b4a.w, b4b.x, b4b.y, b4b.z, b4b.w};
#pragma unroll
      for (int i = 0; i < 4; ++i)
#pragma unroll
        for (int j = 0; j < 8; ++j) acc[i][j] = fmaf(av[i], bv[j], acc[i][j]);
    }
    __syncthreads();
  }
#pragma unroll
  for (int i = 0; i < 4; ++i) {
    int gr = row0 + (ty << 2) + i;
    if (gr < NN) {
      float o[8];
#pragma unroll
      for (int j = 0; j < 8; ++j) {
        int c = c0 + (tx << 3) + j;
        o[j] = fmaxf(acc[i][j] + b1[c], 0.f);
      }
      *(float4*)&hmid[(size_t)gr * 256 + c0 + (tx << 3)] = make_float4(o[0], o[1], o[2], o[3]);
      *(float4*)&hmid[(size_t)gr * 256 + c0 + (tx << 3) + 4] = make_float4(o[4], o[5], o[6], o[7]);
    }
  }
}

// ------------- FFN2: hfin = affine1(h) + hmid@W2 + b2; accumulate BN2 stats
__global__ __launch_bounds__(256)
void ffn2(const float* __restrict__ W2, const float* __restrict__ b2, float* __restrict__ ws) {
  __shared__ float As[32][68];
  __shared__ float Bs[32][128];
  const float* hmid = ws + HMID_OFF;
  const float* h = ws + H_OFF;
  const float* a1 = ws + ST_OFF + 512;
  const float* bb1 = ws + ST_OFF + 640;
  float* hfin = ws + HFIN_OFF;
  float* st = ws + ST_OFF;
  const int tid = threadIdx.x;
  const int tx = tid & 15, ty = tid >> 4;
  const int row0 = blockIdx.x * 64;

  float acc[4][8];
#pragma unroll
  for (int i = 0; i < 4; ++i)
#pragma unroll
    for (int j = 0; j < 8; ++j) acc[i][j] = 0.f;

  for (int k0 = 0; k0 < 256; k0 += 32) {
#pragma unroll
    for (int j = 0; j < 2; ++j) {
      int s = tid + 256 * j;
      int r = s >> 3, kg = (s & 7) << 2;
      int gr = row0 + r;
      float4 v = make_float4(0.f, 0.f, 0.f, 0.f);
      if (gr < NN) v = *(const float4*)&hmid[(size_t)gr * 256 + k0 + kg];
      As[kg + 0][r] = v.x; As[kg + 1][r] = v.y; As[kg + 2][r] = v.z; As[kg + 3][r] = v.w;
    }
#pragma unroll
    for (int j = 0; j < 4; ++j) {
      int s = tid + 256 * j;
      int kk = s >> 5, cg = (s & 31) << 2;
      *(float4*)&Bs[kk][cg] = *(const float4*)&W2[(size_t)(k0 + kk) * 128 + cg];
    }
    __syncthreads();
#pragma unroll
    for (int k = 0; k < 32; ++k) {
      float4 a4 = *(float4*)&As[k][ty << 2];
      float4 b4a = *(float4*)&Bs[k][tx << 3];
      float4 b4b = *(float4*)&Bs[k][(tx << 3) + 4];
      float av[4] = {a4.x, a4.y, a4.z, a4.w};
      float bv[8] = {b4a.x, b4a.y, b4a.z, b4a.w, b4b.x, b4b.y, b4b.z, b4b.w};
#pragma unroll
      for (int i = 0; i < 4; ++i)
#pragma unroll
        for (int j = 0; j < 8; ++j) acc[i][j] = fmaf(av[i], bv[j], acc[i][j]);
    }
    __syncthreads();
  }

  float psum[8] = {0, 0, 0, 0, 0, 0, 0, 0}, psq[8] = {0, 0, 0, 0, 0, 0, 0, 0};
#pragma unroll
  for (int i = 0; i < 4; ++i) {
    int gr = row0 + (ty << 2) + i;
    if (gr < NN) {
      float o[8];
#pragma unroll
      for (int j = 0; j < 8; ++j) {
        int c = (tx << 3) + j;
        float hn = h[(size_t)gr * 128 + c] * a1[c] + bb1[c];
        float v = acc[i][j] + b2[c] + hn;
        o[j] = v;
        psum[j] += v;
        psq[j] += v * v;
      }
      *(float4*)&hfin[(size_t)gr * 128 + (tx << 3)] = make_float4(o[0], o[1], o[2], o[3]);
      *(float4*)&hfin[(size_t)gr * 128 + (tx << 3) + 4] = make_float4(o[4], o[5], o[6], o[7]);
    }
  }
  // block reduction of BN2 stats in Bs (free after last sync)
  float* red = &Bs[0][0];  // 4096 floats
#pragma unroll
  for (int j = 0; j < 8; ++j) {
    red[ty * 128 + (tx << 3) + j] = psum[j];
    red[2048 + ty * 128 + (tx << 3) + j] = psq[j];
  }
  __syncthreads();
  if (tid < 128) {
    float ssum = 0.f, ssq = 0.f;
#pragma unroll
    for (int t = 0; t < 16; ++t) {
      ssum += red[t * 128 + tid];
      ssq += red[2048 + t * 128 + tid];
    }
    atomicAdd(&st[256 + tid], ssum);
    atomicAdd(&st[384 + tid], ssq);
  }
}

// --------------------------- final BN2 apply
__global__ __launch_bounds__(256)
void bn2_apply(const float* __restrict__ ws, float* __restrict__ out) {
  const float* hfin = ws + HFIN_OFF;
  const float* st = ws + ST_OFF;
  const int total4 = NN * 128 / 4;
  for (int i = blockIdx.x * blockDim.x + threadIdx.x; i < total4; i += gridDim.x * blockDim.x) {
    int cg = (i & 31) << 2;
    float4 v = *(const float4*)&hfin[(size_t)i * 4];
    float4 a = *(const float4*)&st[768 + cg];
    float4 b = *(const float4*)&st[896 + cg];
    float4 o;
    o.x = v.x * a.x + b.x; o.y = v.y * a.y + b.y;
    o.z = v.z * a.z + b.z; o.w = v.w * a.w + b.w;
    *(float4*)&out[(size_t)i * 4] = o;
  }
}

extern "C" void kernel_launch(void* const* d_in, const int* in_sizes, int n_in,
                              void* d_out, int out_size, void* d_ws, size_t ws_size,
                              hipStream_t stream) {
  const float* x = (const float*)d_in[0];
  const float* edge_attr = (const float*)d_in[1];
  const void* eidx = d_in[2];
  const float* Wq = (const float*)d_in[3];
  const float* Wk = (const float*)d_in[4];
  const float* We = (const float*)d_in[5];
  const float* Wv = (const float*)d_in[6];
  const float* bn1_g = (const float*)d_in[7];
  const float* bn1_b = (const float*)d_in[8];
  const float* W1 = (const float*)d_in[9];
  const float* b1 = (const float*)d_in[10];
  const float* W2 = (const float*)d_in[11];
  const float* b2 = (const float*)d_in[12];
  const float* bn2_g = (const float*)d_in[13];
  const float* bn2_b = (const float*)d_in[14];
  float* ws = (float*)d_ws;
  float* out = (float*)d_out;

  // zero wV, Z, bn stats (ws is poisoned 0xAA before every call)
  hipMemsetAsync(ws + WV_OFF, 0, (size_t)(6400000 + 400000 + 512) * sizeof(float), stream);

  dim3 b256(256);
  detect_eidx<<<1, 256, 0, stream>>>((const int*)eidx, ws);
  proj_qkv<<<dim3(782, 3), b256, 0, stream>>>(x, Wq, Wk, Wv, ws);
  edge_kernel<<<dim3(9375), b256, 0, stream>>>(edge_attr, eidx, We, ws);
  attn_bn1<<<dim3(512), b256, 0, stream>>>(x, ws);
  bn_finalize<<<1, 128, 0, stream>>>(bn1_g, bn1_b, ws, 0, 512);
  ffn1<<<dim3(782, 2), b256, 0, stream>>>(W1, b1, ws);
  ffn2<<<dim3(782), b256, 0, stream>>>(W2, b2, ws);
  bn_finalize<<<1, 128, 0, stream>>>(bn2_g, bn2_b, ws, 256, 768);
  bn2_apply<<<dim3(2048), b256, 0, stream>>>(ws, out);
}

// Round 6
// 1130.393 us; speedup vs baseline: 2.4965x; 2.4965x over previous
//
#include <hip/hip_runtime.h>
#include <hip/hip_bf16.h>
#include <math.h>
#include <stdint.h>

#define NN 50000
#define EE 600000

// ws layout in floats (max ~102.4 MB, within validated footprint)
#define QH_OFF   0              // Q [N,128]; aggregate overwrites with h
#define K_OFF    6400000        // K [N,128]
#define V_OFF    12800000       // V [N,128]
#define HMID_OFF 6400000        // hmid [N,256] over K+V (dead after aggregate)
#define HFIN_OFF 19200000       // hfin [N,128] over int arrays (dead after aggregate)
#define ROWS_OFF 19200000       // int row_start[50001]
#define CNT_OFF  19260000       // int cnt[50000]
#define CUR_OFF  19310000       // int cursor[50000]  (CNT..CUR contiguous for memset)
#define ELS_OFF  19360000       // int el_src[600000]
#define ELE_OFF  19960000       // int el_e[600000]   (ends 20560000)
#define ST_OFF   25600000       // 1024 floats: sum1 sq1 sum2 sq2 | a1 bb1 a2 bb2
#define FLAG_OFF 25601024       // 1 int: edge_index dtype flag
#define H_OFF    QH_OFF

// ------------------------------------------------ edge_index dtype detection
__global__ void detect_eidx(const int* __restrict__ e32, float* __restrict__ ws) {
  __shared__ int nz;
  if (threadIdx.x == 0) nz = 0;
  __syncthreads();
  if (e32[threadIdx.x * 2 + 1] != 0) atomicAdd(&nz, 1);
  __syncthreads();
  if (threadIdx.x == 0) ((int*)(ws + FLAG_OFF))[0] = (nz == 0) ? 1 : 0;
}

__device__ __forceinline__ int load_idx(const void* eidx, int is64, size_t off) {
  return is64 ? (int)((const long long*)eidx)[off] : ((const int*)eidx)[off];
}

// ---------------------------------------------------------------- CSR build
__global__ __launch_bounds__(256)
void count_deg(const void* __restrict__ eidx, float* __restrict__ ws) {
  int e = blockIdx.x * 256 + threadIdx.x;
  if (e >= EE) return;
  int is64 = ((const int*)(ws + FLAG_OFF))[0];
  int dst = load_idx(eidx, is64, (size_t)EE + e);
  atomicAdd((int*)(ws + CNT_OFF) + dst, 1);
}

__global__ __launch_bounds__(1024)
void scan_deg(float* __restrict__ ws) {
  const int* cnt = (const int*)(ws + CNT_OFF);
  int* rows = (int*)(ws + ROWS_OFF);
  __shared__ int part[1024];
  const int t = threadIdx.x;
  const int base = t * 49;
  int s = 0;
  for (int i = 0; i < 49; ++i) {
    int idx = base + i;
    s += (idx < NN) ? cnt[idx] : 0;
  }
  part[t] = s;
  __syncthreads();
  for (int off = 1; off < 1024; off <<= 1) {
    int v = (t >= off) ? part[t - off] : 0;
    __syncthreads();
    part[t] += v;
    __syncthreads();
  }
  int run = (t == 0) ? 0 : part[t - 1];   // exclusive chunk base
  for (int i = 0; i < 49; ++i) {
    int idx = base + i;
    if (idx < NN) {
      rows[idx] = run;
      run += cnt[idx];
    }
  }
  if (t == 1023) rows[NN] = EE;
}

__global__ __launch_bounds__(256)
void fill_csr(const void* __restrict__ eidx, float* __restrict__ ws) {
  int e = blockIdx.x * 256 + threadIdx.x;
  if (e >= EE) return;
  int is64 = ((const int*)(ws + FLAG_OFF))[0];
  int src = load_idx(eidx, is64, (size_t)e);
  int dst = load_idx(eidx, is64, (size_t)EE + e);
  int p = atomicAdd((int*)(ws + CUR_OFF) + dst, 1);
  int j = ((const int*)(ws + ROWS_OFF))[dst] + p;
  ((int*)(ws + ELS_OFF))[j] = src;
  ((int*)(ws + ELE_OFF))[j] = e;
}

// ---------------------------------------------------------------- proj Q,K,V
__global__ __launch_bounds__(256)
void proj_qkv(const float* __restrict__ x, const float* __restrict__ Wq,
              const float* __restrict__ Wk, const float* __restrict__ Wv,
              float* __restrict__ ws) {
  __shared__ float As[32][68];
  __shared__ float Bs[32][128];
  const int tid = threadIdx.x;
  const int tx = tid & 15, ty = tid >> 4;
  const int row0 = blockIdx.x * 64;
  const float* W = (blockIdx.y == 0) ? Wq : ((blockIdx.y == 1) ? Wk : Wv);
  float* out = ws + ((blockIdx.y == 0) ? QH_OFF : ((blockIdx.y == 1) ? K_OFF : V_OFF));

  float acc[4][8];
#pragma unroll
  for (int i = 0; i < 4; ++i)
#pragma unroll
    for (int j = 0; j < 8; ++j) acc[i][j] = 0.f;

  for (int k0 = 0; k0 < 128; k0 += 32) {
#pragma unroll
    for (int j = 0; j < 2; ++j) {
      int s = tid + 256 * j;
      int r = s >> 3, kg = (s & 7) << 2;
      int gr = row0 + r;
      float4 v = make_float4(0.f, 0.f, 0.f, 0.f);
      if (gr < NN) v = *(const float4*)&x[(size_t)gr * 128 + k0 + kg];
      As[kg + 0][r] = v.x; As[kg + 1][r] = v.y; As[kg + 2][r] = v.z; As[kg + 3][r] = v.w;
    }
#pragma unroll
    for (int j = 0; j < 4; ++j) {
      int s = tid + 256 * j;
      int kk = s >> 5, cg = (s & 31) << 2;
      *(float4*)&Bs[kk][cg] = *(const float4*)&W[(size_t)(k0 + kk) * 128 + cg];
    }
    __syncthreads();
#pragma unroll
    for (int k = 0; k < 32; ++k) {
      float4 a4 = *(float4*)&As[k][ty << 2];
      float4 b4a = *(float4*)&Bs[k][tx << 3];
      float4 b4b = *(float4*)&Bs[k][(tx << 3) + 4];
      float av[4] = {a4.x, a4.y, a4.z, a4.w};
      float bv[8] = {b4a.x, b4a.y, b4a.z, b4a.w, b4b.x, b4b.y, b4b.z, b4b.w};
#pragma unroll
      for (int i = 0; i < 4; ++i)
#pragma unroll
        for (int j = 0; j < 8; ++j) acc[i][j] = fmaf(av[i], bv[j], acc[i][j]);
    }
    __syncthreads();
  }
#pragma unroll
  for (int i = 0; i < 4; ++i) {
    int gr = row0 + (ty << 2) + i;
    if (gr < NN) {
      float4 o0 = make_float4(acc[i][0], acc[i][1], acc[i][2], acc[i][3]);
      float4 o1 = make_float4(acc[i][4], acc[i][5], acc[i][6], acc[i][7]);
      *(float4*)&out[(size_t)gr * 128 + (tx << 3)] = o0;
      *(float4*)&out[(size_t)gr * 128 + (tx << 3) + 4] = o1;
    }
  }
}

// --------------------------------- edge: E_e GEMM + score write (no atomics)
__global__ __launch_bounds__(256)
void edge_score(const float* __restrict__ edge_attr, const void* __restrict__ eidx,
                const float* __restrict__ We, float* __restrict__ ws,
                float* __restrict__ score) {
  __shared__ float As[32][68];
  __shared__ float Bs[32][128];
  __shared__ int s_src[64], s_dst[64];
  __shared__ int s_is64;
  const int tid = threadIdx.x;
  const int tx = tid & 15, ty = tid >> 4;
  const int e0 = blockIdx.x * 64;   // E = 9375*64 exactly

  if (tid == 0) s_is64 = ((const int*)(ws + FLAG_OFF))[0];
  __syncthreads();
  if (tid < 128) {
    int lane = tid & 63;
    size_t off = (tid < 64) ? (size_t)(e0 + lane) : ((size_t)EE + e0 + lane);
    int idx = s_is64 ? (int)((const long long*)eidx)[off]
                     : ((const int*)eidx)[off];
    if (tid < 64) s_src[lane] = idx; else s_dst[lane] = idx;
  }

  float acc[4][8];
#pragma unroll
  for (int i = 0; i < 4; ++i)
#pragma unroll
    for (int j = 0; j < 8; ++j) acc[i][j] = 0.f;

  for (int k0 = 0; k0 < 128; k0 += 32) {
#pragma unroll
    for (int j = 0; j < 2; ++j) {
      int s = tid + 256 * j;
      int r = s >> 3, kg = (s & 7) << 2;
      float4 v = *(const float4*)&edge_attr[(size_t)(e0 + r) * 128 + k0 + kg];
      As[kg + 0][r] = v.x; As[kg + 1][r] = v.y; As[kg + 2][r] = v.z; As[kg + 3][r] = v.w;
    }
#pragma unroll
    for (int j = 0; j < 4; ++j) {
      int s = tid + 256 * j;
      int kk = s >> 5, cg = (s & 31) << 2;
      *(float4*)&Bs[kk][cg] = *(const float4*)&We[(size_t)(k0 + kk) * 128 + cg];
    }
    __syncthreads();
#pragma unroll
    for (int k = 0; k < 32; ++k) {
      float4 a4 = *(float4*)&As[k][ty << 2];
      float4 b4a = *(float4*)&Bs[k][tx << 3];
      float4 b4b = *(float4*)&Bs[k][(tx << 3) + 4];
      float av[4] = {a4.x, a4.y, a4.z, a4.w};
      float bv[8] = {b4a.x, b4a.y, b4a.z, b4a.w, b4b.x, b4b.y, b4b.z, b4b.w};
#pragma unroll
      for (int i = 0; i < 4; ++i)
#pragma unroll
        for (int j = 0; j < 8; ++j) acc[i][j] = fmaf(av[i], bv[j], acc[i][j]);
    }
    __syncthreads();
  }

  const float* Qm = ws + QH_OFF;
  const float* Km = ws + K_OFF;
  const int c0 = tx << 3;

#pragma unroll
  for (int i = 0; i < 4; ++i) {
    const int e = e0 + (ty << 2) + i;
    const int src = s_src[(ty << 2) + i];
    const int dst = s_dst[(ty << 2) + i];
    const float* Kp = Km + (size_t)src * 128 + c0;
    const float* Qp = Qm + (size_t)dst * 128 + c0;
    float4 ka = *(const float4*)Kp, kb = *(const float4*)(Kp + 4);
    float4 qa = *(const float4*)Qp, qb = *(const float4*)(Qp + 4);
    float p = acc[i][0] * ka.x * qa.x + acc[i][1] * ka.y * qa.y
            + acc[i][2] * ka.z * qa.z + acc[i][3] * ka.w * qa.w
            + acc[i][4] * kb.x * qb.x + acc[i][5] * kb.y * qb.y
            + acc[i][6] * kb.z * qb.z + acc[i][7] * kb.w * qb.w;
    p *= 0.25f;                         // 1/sqrt(DH)
    p += __shfl_xor(p, 1);              // combine the two half-head partials
    float sc = __expf(fminf(fmaxf(p, -5.f), 5.f));
    if ((tx & 1) == 0) score[(size_t)e * 8 + (tx >> 1)] = sc;
  }
}

// --------- aggregate: CSR gather -> h = x + wV/(Z+1e-6), fused BN1 stats
__global__ __launch_bounds__(256)
void aggregate(const float* __restrict__ x, const float* __restrict__ score,
               float* __restrict__ ws) {
  const int* rows = (const int*)(ws + ROWS_OFF);
  const int* els  = (const int*)(ws + ELS_OFF);
  const int* ele  = (const int*)(ws + ELE_OFF);
  const float* V  = ws + V_OFF;
  float* h = ws + H_OFF;
  float* st = ws + ST_OFF;
  const int tid = threadIdx.x;
  const int l = tid & 31;       // lane in 32-lane group
  const int g = tid >> 5;       // 8 groups per block
  const int c = l << 2;         // column quad
  const int h8 = l >> 2;        // head

  float s4[4] = {0.f, 0.f, 0.f, 0.f}, q4[4] = {0.f, 0.f, 0.f, 0.f};

  for (int d = blockIdx.x * 8 + g; d < NN; d += gridDim.x * 8) {
    const int j0 = rows[d], j1 = rows[d + 1];
    float a0 = 0.f, a1 = 0.f, a2 = 0.f, a3 = 0.f, z = 0.f;
    int e = 0, src = 0;
    if (j0 < j1) { e = ele[j0]; src = els[j0]; }
    for (int j = j0; j < j1; ++j) {
      int e2 = 0, src2 = 0;
      if (j + 1 < j1) { e2 = ele[j + 1]; src2 = els[j + 1]; }
      float sc = score[(size_t)e * 8 + h8];
      float4 v4 = *(const float4*)&V[(size_t)src * 128 + c];
      a0 = fmaf(v4.x, sc, a0); a1 = fmaf(v4.y, sc, a1);
      a2 = fmaf(v4.z, sc, a2); a3 = fmaf(v4.w, sc, a3);
      z += sc;
      e = e2; src = src2;
    }
    float zi = 1.f / (z + 1e-6f);
    float4 xv = *(const float4*)&x[(size_t)d * 128 + c];
    float4 hv;
    hv.x = xv.x + a0 * zi; hv.y = xv.y + a1 * zi;
    hv.z = xv.z + a2 * zi; hv.w = xv.w + a3 * zi;
    *(float4*)&h[(size_t)d * 128 + c] = hv;
    s4[0] += hv.x; s4[1] += hv.y; s4[2] += hv.z; s4[3] += hv.w;
    q4[0] += hv.x * hv.x; q4[1] += hv.y * hv.y;
    q4[2] += hv.z * hv.z; q4[3] += hv.w * hv.w;
  }

  __shared__ float red[8][32][8];
#pragma unroll
  for (int j = 0; j < 4; ++j) { red[g][l][j] = s4[j]; red[g][l][4 + j] = q4[j]; }
  __syncthreads();
  if (tid < 32) {
    float ss[4] = {0.f, 0.f, 0.f, 0.f}, qq[4] = {0.f, 0.f, 0.f, 0.f};
    for (int gg = 0; gg < 8; ++gg)
#pragma unroll
      for (int j = 0; j < 4; ++j) { ss[j] += red[gg][tid][j]; qq[j] += red[gg][tid][4 + j]; }
#pragma unroll
    for (int j = 0; j < 4; ++j) {
      atomicAdd(&st[(tid << 2) + j], ss[j]);
      atomicAdd(&st[128 + (tid << 2) + j], qq[j]);
    }
  }
}

// --------------------------- BN finalize: a = g/sqrt(var+eps), b = beta - mu*a
__global__ void bn_finalize(const float* __restrict__ g, const float* __restrict__ beta,
                            float* __restrict__ ws, int sum_off, int out_off) {
  float* st = ws + ST_OFF;
  int c = threadIdx.x;
  float mu = st[sum_off + c] / (float)NN;
  float var = st[sum_off + 128 + c] / (float)NN - mu * mu;
  float istd = 1.f / sqrtf(var + 1e-5f);
  float a = g[c] * istd;
  st[out_off + c] = a;
  st[out_off + 128 + c] = beta[c] - mu * a;
}

// --------------------------- FFN1: hmid = relu(affine1(h) @ W1 + b1)
__global__ __launch_bounds__(256)
void ffn1(const float* __restrict__ W1, const float* __restrict__ b1, float* __restrict__ ws) {
  __shared__ float As[32][68];
  __shared__ float Bs[32][128];
  const float* h = ws + H_OFF;
  const float* a1 = ws + ST_OFF + 512;
  const float* bb1 = ws + ST_OFF + 640;
  float* hmid = ws + HMID_OFF;
  const int tid = threadIdx.x;
  const int tx = tid & 15, ty = tid >> 4;
  const int row0 = blockIdx.x * 64;
  const int c0 = blockIdx.y * 128;

  float acc[4][8];
#pragma unroll
  for (int i = 0; i < 4; ++i)
#pragma unroll
    for (int j = 0; j < 8; ++j) acc[i][j] = 0.f;

  for (int k0 = 0; k0 < 128; k0 += 32) {
#pragma unroll
    for (int j = 0; j < 2; ++j) {
      int s = tid + 256 * j;
      int r = s >> 3, kg = (s & 7) << 2;
      int gr = row0 + r;
      float4 v = make_float4(0.f, 0.f, 0.f, 0.f);
      if (gr < NN) {
        v = *(const float4*)&h[(size_t)gr * 128 + k0 + kg];
        float4 aa = *(const float4*)&a1[k0 + kg];
        float4 bb = *(const float4*)&bb1[k0 + kg];
        v.x = v.x * aa.x + bb.x; v.y = v.y * aa.y + bb.y;
        v.z = v.z * aa.z + bb.z; v.w = v.w * aa.w + bb.w;
      }
      As[kg + 0][r] = v.x; As[kg + 1][r] = v.y; As[kg + 2][r] = v.z; As[kg + 3][r] = v.w;
    }
#pragma unroll
    for (int j = 0; j < 4; ++j) {
      int s = tid + 256 * j;
      int kk = s >> 5, cg = (s & 31) << 2;
      *(float4*)&Bs[kk][cg] = *(const float4*)&W1[(size_t)(k0 + kk) * 256 + c0 + cg];
    }
    __syncthreads();
#pragma unroll
    for (int k = 0; k < 32; ++k) {
      float4 a4 = *(float4*)&As[k][ty << 2];
      float4 b4a = *(float4*)&Bs[k][tx << 3];
      float4 b4b = *(float4*)&Bs[k][(tx << 3) + 4];
      float av[4] = {a4.x, a4.y, a4.z, a4.w};
      float bv[8] = {b4a.x, b4a.y, b4a.z, b4a.w, b4b.x, b4b.y, b4b.z, b4b.w};
#pragma unroll
      for (int i = 0; i < 4; ++i)
#pragma unroll
        for (int j = 0; j < 8; ++j) acc[i][j] = fmaf(av[i], bv[j], acc[i][j]);
    }
    __syncthreads();
  }
#pragma unroll
  for (int i = 0; i < 4; ++i) {
    int gr = row0 + (ty << 2) + i;
    if (gr < NN) {
      float o[8];
#pragma unroll
      for (int j = 0; j < 8; ++j) {
        int c = c0 + (tx << 3) + j;
        o[j] = fmaxf(acc[i][j] + b1[c], 0.f);
      }
      *(float4*)&hmid[(size_t)gr * 256 + c0 + (tx << 3)] = make_float4(o[0], o[1], o[2], o[3]);
      *(float4*)&hmid[(size_t)gr * 256 + c0 + (tx << 3) + 4] = make_float4(o[4], o[5], o[6], o[7]);
    }
  }
}

// ------------- FFN2: hfin = affine1(h) + hmid@W2 + b2; accumulate BN2 stats
__global__ __launch_bounds__(256)
void ffn2(const float* __restrict__ W2, const float* __restrict__ b2, float* __restrict__ ws) {
  __shared__ float As[32][68];
  __shared__ float Bs[32][128];
  const float* hmid = ws + HMID_OFF;
  const float* h = ws + H_OFF;
  const float* a1 = ws + ST_OFF + 512;
  const float* bb1 = ws + ST_OFF + 640;
  float* hfin = ws + HFIN_OFF;
  float* st = ws + ST_OFF;
  const int tid = threadIdx.x;
  const int tx = tid & 15, ty = tid >> 4;
  const int row0 = blockIdx.x * 64;

  float acc[4][8];
#pragma unroll
  for (int i = 0; i < 4; ++i)
#pragma unroll
    for (int j = 0; j < 8; ++j) acc[i][j] = 0.f;

  for (int k0 = 0; k0 < 256; k0 += 32) {
#pragma unroll
    for (int j = 0; j < 2; ++j) {
      int s = tid + 256 * j;
      int r = s >> 3, kg = (s & 7) << 2;
      int gr = row0 + r;
      float4 v = make_float4(0.f, 0.f, 0.f, 0.f);
      if (gr < NN) v = *(const float4*)&hmid[(size_t)gr * 256 + k0 + kg];
      As[kg + 0][r] = v.x; As[kg + 1][r] = v.y; As[kg + 2][r] = v.z; As[kg + 3][r] = v.w;
    }
#pragma unroll
    for (int j = 0; j < 4; ++j) {
      int s = tid + 256 * j;
      int kk = s >> 5, cg = (s & 31) << 2;
      *(float4*)&Bs[kk][cg] = *(const float4*)&W2[(size_t)(k0 + kk) * 128 + cg];
    }
    __syncthreads();
#pragma unroll
    for (int k = 0; k < 32; ++k) {
      float4 a4 = *(float4*)&As[k][ty << 2];
      float4 b4a = *(float4*)&Bs[k][tx << 3];
      float4 b4b = *(float4*)&Bs[k][(tx << 3) + 4];
      float av[4] = {a4.x, a4.y, a4.z, a4.w};
      float bv[8] = {b4a.x, b4a.y, b4a.z, b4a.w, b4b.x, b4b.y, b4b.z, b4b.w};
#pragma unroll
      for (int i = 0; i < 4; ++i)
#pragma unroll
        for (int j = 0; j < 8; ++j) acc[i][j] = fmaf(av[i], bv[j], acc[i][j]);
    }
    __syncthreads();
  }

  float psum[8] = {0, 0, 0, 0, 0, 0, 0, 0}, psq[8] = {0, 0, 0, 0, 0, 0, 0, 0};
#pragma unroll
  for (int i = 0; i < 4; ++i) {
    int gr = row0 + (ty << 2) + i;
    if (gr < NN) {
      float o[8];
#pragma unroll
      for (int j = 0; j < 8; ++j) {
        int c = (tx << 3) + j;
        float hn = h[(size_t)gr * 128 + c] * a1[c] + bb1[c];
        float v = acc[i][j] + b2[c] + hn;
        o[j] = v;
        psum[j] += v;
        psq[j] += v * v;
      }
      *(float4*)&hfin[(size_t)gr * 128 + (tx << 3)] = make_float4(o[0], o[1], o[2], o[3]);
      *(float4*)&hfin[(size_t)gr * 128 + (tx << 3) + 4] = make_float4(o[4], o[5], o[6], o[7]);
    }
  }
  float* red = &Bs[0][0];  // 4096 floats, free after last sync
#pragma unroll
  for (int j = 0; j < 8; ++j) {
    red[ty * 128 + (tx << 3) + j] = psum[j];
    red[2048 + ty * 128 + (tx << 3) + j] = psq[j];
  }
  __syncthreads();
  if (tid < 128) {
    float ssum = 0.f, ssq = 0.f;
#pragma unroll
    for (int t = 0; t < 16; ++t) {
      ssum += red[t * 128 + tid];
      ssq += red[2048 + t * 128 + tid];
    }
    atomicAdd(&st[256 + tid], ssum);
    atomicAdd(&st[384 + tid], ssq);
  }
}

// --------------------------- final BN2 apply
__global__ __launch_bounds__(256)
void bn2_apply(const float* __restrict__ ws, float* __restrict__ out) {
  const float* hfin = ws + HFIN_OFF;
  const float* st = ws + ST_OFF;
  const int total4 = NN * 128 / 4;
  for (int i = blockIdx.x * blockDim.x + threadIdx.x; i < total4; i += gridDim.x * blockDim.x) {
    int cg = (i & 31) << 2;
    float4 v = *(const float4*)&hfin[(size_t)i * 4];
    float4 a = *(const float4*)&st[768 + cg];
    float4 b = *(const float4*)&st[896 + cg];
    float4 o;
    o.x = v.x * a.x + b.x; o.y = v.y * a.y + b.y;
    o.z = v.z * a.z + b.z; o.w = v.w * a.w + b.w;
    *(float4*)&out[(size_t)i * 4] = o;
  }
}

extern "C" void kernel_launch(void* const* d_in, const int* in_sizes, int n_in,
                              void* d_out, int out_size, void* d_ws, size_t ws_size,
                              hipStream_t stream) {
  const float* x = (const float*)d_in[0];
  const float* edge_attr = (const float*)d_in[1];
  const void* eidx = d_in[2];
  const float* Wq = (const float*)d_in[3];
  const float* Wk = (const float*)d_in[4];
  const float* We = (const float*)d_in[5];
  const float* Wv = (const float*)d_in[6];
  const float* bn1_g = (const float*)d_in[7];
  const float* bn1_b = (const float*)d_in[8];
  const float* W1 = (const float*)d_in[9];
  const float* b1 = (const float*)d_in[10];
  const float* W2 = (const float*)d_in[11];
  const float* b2 = (const float*)d_in[12];
  const float* bn2_g = (const float*)d_in[13];
  const float* bn2_b = (const float*)d_in[14];
  float* ws = (float*)d_ws;
  float* out = (float*)d_out;
  float* score = out;   // d_out doubles as score scratch (4.8M <= 6.4M floats)

  // zero cnt+cursor (contiguous 100k ints) and BN stat accumulators
  hipMemsetAsync(ws + CNT_OFF, 0, 100000 * sizeof(int), stream);
  hipMemsetAsync(ws + ST_OFF, 0, 512 * sizeof(float), stream);

  dim3 b256(256);
  detect_eidx<<<1, 256, 0, stream>>>((const int*)eidx, ws);
  count_deg<<<dim3(2344), b256, 0, stream>>>(eidx, ws);
  scan_deg<<<1, 1024, 0, stream>>>(ws);
  fill_csr<<<dim3(2344), b256, 0, stream>>>(eidx, ws);
  proj_qkv<<<dim3(782, 3), b256, 0, stream>>>(x, Wq, Wk, Wv, ws);
  edge_score<<<dim3(9375), b256, 0, stream>>>(edge_attr, eidx, We, ws, score);
  aggregate<<<dim3(512), b256, 0, stream>>>(x, score, ws);
  bn_finalize<<<1, 128, 0, stream>>>(bn1_g, bn1_b, ws, 0, 512);
  ffn1<<<dim3(782, 2), b256, 0, stream>>>(W1, b1, ws);
  ffn2<<<dim3(782), b256, 0, stream>>>(W2, b2, ws);
  bn_finalize<<<1, 128, 0, stream>>>(bn2_g, bn2_b, ws, 256, 768);
  bn2_apply<<<dim3(2048), b256, 0, stream>>>(ws, out);
}

// Round 9
// 1099.799 us; speedup vs baseline: 2.5659x; 1.0278x over previous
//
#include <hip/hip_runtime.h>
#include <hip/hip_bf16.h>
#include <math.h>
#include <stdint.h>

#define NN 50000
#define EE 600000

// ws layout in floats (max ~102.4 MB, within validated footprint)
#define QH_OFF   0              // Q [N,128]; aggregate overwrites with h
#define K_OFF    6400000        // K [N,128]
#define V_OFF    12800000       // V [N,128]
#define HMID_OFF 6400000        // hmid [N,256] over K+V (dead after aggregate)
#define HFIN_OFF 19200000       // hfin [N,128] over int arrays (dead after aggregate)
#define ROWS_OFF 19200000       // int row_start[50001]
#define CNT_OFF  19260000       // int cnt[50000]
#define CUR_OFF  19310000       // int cursor[50000]  (CNT..CUR contiguous for memset)
#define ELS_OFF  19360000       // int el_src[600000]
#define ELE_OFF  19960000       // int el_e[600000]   (ends 20560000)
#define ST_OFF   25600000       // 1024 floats: sum1 sq1 sum2 sq2 | a1 bb1 a2 bb2
#define FLAG_OFF 25601024       // 1 int: edge_index dtype flag
#define H_OFF    QH_OFF

typedef short s16x8 __attribute__((ext_vector_type(8)));   // 8 bf16 in 4 VGPRs
typedef float f32x4 __attribute__((ext_vector_type(4)));

__device__ __forceinline__ short f2bf(float f) {   // RNE fp32 -> bf16
  union { float f; unsigned u; } v; v.f = f;
  unsigned r = v.u + 0x7FFFu + ((v.u >> 16) & 1u);
  return (short)(r >> 16);
}

// ------------------------------------------------ edge_index dtype detection
__global__ void detect_eidx(const int* __restrict__ e32, float* __restrict__ ws) {
  __shared__ int nz;
  if (threadIdx.x == 0) nz = 0;
  __syncthreads();
  if (e32[threadIdx.x * 2 + 1] != 0) atomicAdd(&nz, 1);
  __syncthreads();
  if (threadIdx.x == 0) ((int*)(ws + FLAG_OFF))[0] = (nz == 0) ? 1 : 0;
}

__device__ __forceinline__ int load_idx(const void* eidx, int is64, size_t off) {
  return is64 ? (int)((const long long*)eidx)[off] : ((const int*)eidx)[off];
}

// ---------------------------------------------------------------- CSR build
__global__ __launch_bounds__(256)
void count_deg(const void* __restrict__ eidx, float* __restrict__ ws) {
  int e = blockIdx.x * 256 + threadIdx.x;
  if (e >= EE) return;
  int is64 = ((const int*)(ws + FLAG_OFF))[0];
  int dst = load_idx(eidx, is64, (size_t)EE + e);
  atomicAdd((int*)(ws + CNT_OFF) + dst, 1);
}

__global__ __launch_bounds__(1024)
void scan_deg(float* __restrict__ ws) {
  const int* cnt = (const int*)(ws + CNT_OFF);
  int* rows = (int*)(ws + ROWS_OFF);
  __shared__ int part[1024];
  const int t = threadIdx.x;
  const int base = t * 49;
  int s = 0;
  for (int i = 0; i < 49; ++i) {
    int idx = base + i;
    s += (idx < NN) ? cnt[idx] : 0;
  }
  part[t] = s;
  __syncthreads();
  for (int off = 1; off < 1024; off <<= 1) {
    int v = (t >= off) ? part[t - off] : 0;
    __syncthreads();
    part[t] += v;
    __syncthreads();
  }
  int run = (t == 0) ? 0 : part[t - 1];   // exclusive chunk base
  for (int i = 0; i < 49; ++i) {
    int idx = base + i;
    if (idx < NN) {
      rows[idx] = run;
      run += cnt[idx];
    }
  }
  if (t == 1023) rows[NN] = EE;
}

__global__ __launch_bounds__(256)
void fill_csr(const void* __restrict__ eidx, float* __restrict__ ws) {
  int e = blockIdx.x * 256 + threadIdx.x;
  if (e >= EE) return;
  int is64 = ((const int*)(ws + FLAG_OFF))[0];
  int src = load_idx(eidx, is64, (size_t)e);
  int dst = load_idx(eidx, is64, (size_t)EE + e);
  int p = atomicAdd((int*)(ws + CUR_OFF) + dst, 1);
  int j = ((const int*)(ws + ROWS_OFF))[dst] + p;
  ((int*)(ws + ELS_OFF))[j] = src;
  ((int*)(ws + ELE_OFF))[j] = e;
}

// ---------------------------------------------------------------- proj Q,K,V
__global__ __launch_bounds__(256)
void proj_qkv(const float* __restrict__ x, const float* __restrict__ Wq,
              const float* __restrict__ Wk, const float* __restrict__ Wv,
              float* __restrict__ ws) {
  __shared__ float As[32][68];
  __shared__ float Bs[32][128];
  const int tid = threadIdx.x;
  const int tx = tid & 15, ty = tid >> 4;
  const int row0 = blockIdx.x * 64;
  const float* W = (blockIdx.y == 0) ? Wq : ((blockIdx.y == 1) ? Wk : Wv);
  float* out = ws + ((blockIdx.y == 0) ? QH_OFF : ((blockIdx.y == 1) ? K_OFF : V_OFF));

  float acc[4][8];
#pragma unroll
  for (int i = 0; i < 4; ++i)
#pragma unroll
    for (int j = 0; j < 8; ++j) acc[i][j] = 0.f;

  for (int k0 = 0; k0 < 128; k0 += 32) {
#pragma unroll
    for (int j = 0; j < 2; ++j) {
      int s = tid + 256 * j;
      int r = s >> 3, kg = (s & 7) << 2;
      int gr = row0 + r;
      float4 v = make_float4(0.f, 0.f, 0.f, 0.f);
      if (gr < NN) v = *(const float4*)&x[(size_t)gr * 128 + k0 + kg];
      As[kg + 0][r] = v.x; As[kg + 1][r] = v.y; As[kg + 2][r] = v.z; As[kg + 3][r] = v.w;
    }
#pragma unroll
    for (int j = 0; j < 4; ++j) {
      int s = tid + 256 * j;
      int kk = s >> 5, cg = (s & 31) << 2;
      *(float4*)&Bs[kk][cg] = *(const float4*)&W[(size_t)(k0 + kk) * 128 + cg];
    }
    __syncthreads();
#pragma unroll
    for (int k = 0; k < 32; ++k) {
      float4 a4 = *(float4*)&As[k][ty << 2];
      float4 b4a = *(float4*)&Bs[k][tx << 3];
      float4 b4b = *(float4*)&Bs[k][(tx << 3) + 4];
      float av[4] = {a4.x, a4.y, a4.z, a4.w};
      float bv[8] = {b4a.x, b4a.y, b4a.z, b4a.w, b4b.x, b4b.y, b4b.z, b4b.w};
#pragma unroll
      for (int i = 0; i < 4; ++i)
#pragma unroll
        for (int j = 0; j < 8; ++j) acc[i][j] = fmaf(av[i], bv[j], acc[i][j]);
    }
    __syncthreads();
  }
#pragma unroll
  for (int i = 0; i < 4; ++i) {
    int gr = row0 + (ty << 2) + i;
    if (gr < NN) {
      float4 o0 = make_float4(acc[i][0], acc[i][1], acc[i][2], acc[i][3]);
      float4 o1 = make_float4(acc[i][4], acc[i][5], acc[i][6], acc[i][7]);
      *(float4*)&out[(size_t)gr * 128 + (tx << 3)] = o0;
      *(float4*)&out[(size_t)gr * 128 + (tx << 3) + 4] = o1;
    }
  }
}

// ---- edge: E_e via bf16 MFMA (D' = We^T · edge^T) + score write (no atomics)
// Per block: 64 edges. 4 waves, wave w owns edges e0+w*16 .. +15.
// LDS holds We^T as bf16, row n (out dim), stride 136 halfwords (272B pad).
__global__ __launch_bounds__(256)
void edge_score(const float* __restrict__ edge_attr, const void* __restrict__ eidx,
                const float* __restrict__ We, float* __restrict__ ws,
                float* __restrict__ score) {
  __shared__ short lds_bt[128 * 136];   // We^T bf16, [n][k] stride 136
  __shared__ int s_src[64], s_dst[64];
  __shared__ int s_is64;
  const int tid = threadIdx.x;
  const int e0 = blockIdx.x * 64;       // E = 9375*64 exactly
  const int w = tid >> 6;               // wave id 0..3
  const int l = tid & 63;               // lane
  const int le = l & 15;                // edge within wave strip / frag col
  const int g = l >> 4;                 // 4-lane-group = k-chunk / row-group

  if (tid == 0) s_is64 = ((const int*)(ws + FLAG_OFF))[0];
  __syncthreads();
  if (tid < 128) {
    int lane = tid & 63;
    size_t off = (tid < 64) ? (size_t)(e0 + lane) : ((size_t)EE + e0 + lane);
    int idx = s_is64 ? (int)((const long long*)eidx)[off]
                     : ((const int*)eidx)[off];
    if (tid < 64) s_src[lane] = idx; else s_dst[lane] = idx;
  }

  // stage We^T -> LDS bf16: lds_bt[n*136 + k] = bf16(We[k][n])
#pragma unroll
  for (int i = 0; i < 4; ++i) {
    const int k = i * 32 + (tid & 15) * 2;
    const int n0 = (tid >> 4) * 8;
    float4 a0 = *(const float4*)&We[(size_t)k * 128 + n0];
    float4 a1 = *(const float4*)&We[(size_t)k * 128 + n0 + 4];
    float4 b0 = *(const float4*)&We[(size_t)(k + 1) * 128 + n0];
    float4 b1 = *(const float4*)&We[(size_t)(k + 1) * 128 + n0 + 4];
    float av[8] = {a0.x, a0.y, a0.z, a0.w, a1.x, a1.y, a1.z, a1.w};
    float bv[8] = {b0.x, b0.y, b0.z, b0.w, b1.x, b1.y, b1.z, b1.w};
#pragma unroll
    for (int j = 0; j < 8; ++j) {
      unsigned lo16 = (unsigned short)f2bf(av[j]);
      unsigned hi16 = (unsigned short)f2bf(bv[j]);
      *(unsigned*)&lds_bt[(n0 + j) * 136 + k] = lo16 | (hi16 << 16);
    }
  }
  __syncthreads();

  // MFMA loop: acc[ct] = E^T tile [n=ct*16..+15][e=wave strip]
  f32x4 acc[8];
#pragma unroll
  for (int ct = 0; ct < 8; ++ct) acc[ct] = (f32x4){0.f, 0.f, 0.f, 0.f};

  const float* ep = edge_attr + (size_t)(e0 + w * 16 + le) * 128;
#pragma unroll
  for (int k0i = 0; k0i < 4; ++k0i) {
    const int k0 = k0i * 32;
    // B' frag: edge^T [k][e]; lane holds edge row le, k = k0+g*8 .. +7
    float4 blo = *(const float4*)&ep[k0 + g * 8];
    float4 bhi = *(const float4*)&ep[k0 + g * 8 + 4];
    s16x8 bfrag;
    bfrag[0] = f2bf(blo.x); bfrag[1] = f2bf(blo.y);
    bfrag[2] = f2bf(blo.z); bfrag[3] = f2bf(blo.w);
    bfrag[4] = f2bf(bhi.x); bfrag[5] = f2bf(bhi.y);
    bfrag[6] = f2bf(bhi.z); bfrag[7] = f2bf(bhi.w);
#pragma unroll
    for (int ct = 0; ct < 8; ++ct) {
      // A' frag: We^T row n = ct*16+le, k = k0+g*8 .. +7  (b128, padded stride)
      s16x8 afrag = *(const s16x8*)&lds_bt[(ct * 16 + le) * 136 + k0 + g * 8];
      acc[ct] = __builtin_amdgcn_mfma_f32_16x16x32_bf16(afrag, bfrag, acc[ct], 0, 0, 0);
    }
  }

  // epilogue: lane holds E[e][ct*16 + g*4 .. +3] in acc[ct]
  const float* Qm = ws + QH_OFF;
  const float* Km = ws + K_OFF;
  const int e = e0 + w * 16 + le;
  const int src = s_src[w * 16 + le];
  const int dst = s_dst[w * 16 + le];
  float out8[8];
#pragma unroll
  for (int ct = 0; ct < 8; ++ct) {
    f32x4 kv = *(const f32x4*)&Km[(size_t)src * 128 + ct * 16 + g * 4];
    f32x4 qv = *(const f32x4*)&Qm[(size_t)dst * 128 + ct * 16 + g * 4];
    float part = acc[ct][0] * kv[0] * qv[0] + acc[ct][1] * kv[1] * qv[1]
               + acc[ct][2] * kv[2] * qv[2] + acc[ct][3] * kv[3] * qv[3];
    part += __shfl_xor(part, 16);       // sum 4 g-groups holding this (e,head)
    part += __shfl_xor(part, 32);
    float p = part * 0.25f;             // 1/sqrt(DH)
    out8[ct] = __expf(fminf(fmaxf(p, -5.f), 5.f));
  }
  if (g == 0) {
    *(float4*)&score[(size_t)e * 8] = make_float4(out8[0], out8[1], out8[2], out8[3]);
    *(float4*)&score[(size_t)e * 8 + 4] = make_float4(out8[4], out8[5], out8[6], out8[7]);
  }
}

// --------- aggregate: CSR gather -> h = x + wV/(Z+1e-6), fused BN1 stats
__global__ __launch_bounds__(256)
void aggregate(const float* __restrict__ x, const float* __restrict__ score,
               float* __restrict__ ws) {
  const int* rows = (const int*)(ws + ROWS_OFF);
  const int* els  = (const int*)(ws + ELS_OFF);
  const int* ele  = (const int*)(ws + ELE_OFF);
  const float* V  = ws + V_OFF;
  float* h = ws + H_OFF;
  float* st = ws + ST_OFF;
  const int tid = threadIdx.x;
  const int l = tid & 31;       // lane in 32-lane group
  const int g = tid >> 5;       // 8 groups per block
  const int c = l << 2;         // column quad
  const int h8 = l >> 2;        // head

  float s4[4] = {0.f, 0.f, 0.f, 0.f}, q4[4] = {0.f, 0.f, 0.f, 0.f};

  for (int d = blockIdx.x * 8 + g; d < NN; d += gridDim.x * 8) {
    const int j0 = rows[d], j1 = rows[d + 1];
    float a0 = 0.f, a1 = 0.f, a2 = 0.f, a3 = 0.f, z = 0.f;
    int e = 0, src = 0;
    if (j0 < j1) { e = ele[j0]; src = els[j0]; }
    for (int j = j0; j < j1; ++j) {
      int e2 = 0, src2 = 0;
      if (j + 1 < j1) { e2 = ele[j + 1]; src2 = els[j + 1]; }
      float sc = score[(size_t)e * 8 + h8];
      float4 v4 = *(const float4*)&V[(size_t)src * 128 + c];
      a0 = fmaf(v4.x, sc, a0); a1 = fmaf(v4.y, sc, a1);
      a2 = fmaf(v4.z, sc, a2); a3 = fmaf(v4.w, sc, a3);
      z += sc;
      e = e2; src = src2;
    }
    float zi = 1.f / (z + 1e-6f);
    float4 xv = *(const float4*)&x[(size_t)d * 128 + c];
    float4 hv;
    hv.x = xv.x + a0 * zi; hv.y = xv.y + a1 * zi;
    hv.z = xv.z + a2 * zi; hv.w = xv.w + a3 * zi;
    *(float4*)&h[(size_t)d * 128 + c] = hv;
    s4[0] += hv.x; s4[1] += hv.y; s4[2] += hv.z; s4[3] += hv.w;
    q4[0] += hv.x * hv.x; q4[1] += hv.y * hv.y;
    q4[2] += hv.z * hv.z; q4[3] += hv.w * hv.w;
  }

  __shared__ float red[8][32][8];
#pragma unroll
  for (int j = 0; j < 4; ++j) { red[g][l][j] = s4[j]; red[g][l][4 + j] = q4[j]; }
  __syncthreads();
  if (tid < 32) {
    float ss[4] = {0.f, 0.f, 0.f, 0.f}, qq[4] = {0.f, 0.f, 0.f, 0.f};
    for (int gg = 0; gg < 8; ++gg)
#pragma unroll
      for (int j = 0; j < 4; ++j) { ss[j] += red[gg][tid][j]; qq[j] += red[gg][tid][4 + j]; }
#pragma unroll
    for (int j = 0; j < 4; ++j) {
      atomicAdd(&st[(tid << 2) + j], ss[j]);
      atomicAdd(&st[128 + (tid << 2) + j], qq[j]);
    }
  }
}

// --------------------------- BN finalize: a = g/sqrt(var+eps), b = beta - mu*a
__global__ void bn_finalize(const float* __restrict__ g, const float* __restrict__ beta,
                            float* __restrict__ ws, int sum_off, int out_off) {
  float* st = ws + ST_OFF;
  int c = threadIdx.x;
  float mu = st[sum_off + c] / (float)NN;
  float var = st[sum_off + 128 + c] / (float)NN - mu * mu;
  float istd = 1.f / sqrtf(var + 1e-5f);
  float a = g[c] * istd;
  st[out_off + c] = a;
  st[out_off + 128 + c] = beta[c] - mu * a;
}

// --------------------------- FFN1: hmid = relu(affine1(h) @ W1 + b1)
__global__ __launch_bounds__(256)
void ffn1(const float* __restrict__ W1, const float* __restrict__ b1, float* __restrict__ ws) {
  __shared__ float As[32][68];
  __shared__ float Bs[32][128];
  const float* h = ws + H_OFF;
  const float* a1 = ws + ST_OFF + 512;
  const float* bb1 = ws + ST_OFF + 640;
  float* hmid = ws + HMID_OFF;
  const int tid = threadIdx.x;
  const int tx = tid & 15, ty = tid >> 4;
  const int row0 = blockIdx.x * 64;
  const int c0 = blockIdx.y * 128;

  float acc[4][8];
#pragma unroll
  for (int i = 0; i < 4; ++i)
#pragma unroll
    for (int j = 0; j < 8; ++j) acc[i][j] = 0.f;

  for (int k0 = 0; k0 < 128; k0 += 32) {
#pragma unroll
    for (int j = 0; j < 2; ++j) {
      int s = tid + 256 * j;
      int r = s >> 3, kg = (s & 7) << 2;
      int gr = row0 + r;
      float4 v = make_float4(0.f, 0.f, 0.f, 0.f);
      if (gr < NN) {
        v = *(const float4*)&h[(size_t)gr * 128 + k0 + kg];
        float4 aa = *(const float4*)&a1[k0 + kg];
        float4 bb = *(const float4*)&bb1[k0 + kg];
        v.x = v.x * aa.x + bb.x; v.y = v.y * aa.y + bb.y;
        v.z = v.z * aa.z + bb.z; v.w = v.w * aa.w + bb.w;
      }
      As[kg + 0][r] = v.x; As[kg + 1][r] = v.y; As[kg + 2][r] = v.z; As[kg + 3][r] = v.w;
    }
#pragma unroll
    for (int j = 0; j < 4; ++j) {
      int s = tid + 256 * j;
      int kk = s >> 5, cg = (s & 31) << 2;
      *(float4*)&Bs[kk][cg] = *(const float4*)&W1[(size_t)(k0 + kk) * 256 + c0 + cg];
    }
    __syncthreads();
#pragma unroll
    for (int k = 0; k < 32; ++k) {
      float4 a4 = *(float4*)&As[k][ty << 2];
      float4 b4a = *(float4*)&Bs[k][tx << 3];
      float4 b4b = *(float4*)&Bs[k][(tx << 3) + 4];
      float av[4] = {a4.x, a4.y, a4.z, a4.w};
      float bv[8] = {b4a.x, b4a.y, b4a.z, b4a.w, b4b.x, b4b.y, b4b.z, b4b.w};
#pragma unroll
      for (int i = 0; i < 4; ++i)
#pragma unroll
        for (int j = 0; j < 8; ++j) acc[i][j] = fmaf(av[i], bv[j], acc[i][j]);
    }
    __syncthreads();
  }
#pragma unroll
  for (int i = 0; i < 4; ++i) {
    int gr = row0 + (ty << 2) + i;
    if (gr < NN) {
      float o[8];
#pragma unroll
      for (int j = 0; j < 8; ++j) {
        int c = c0 + (tx << 3) + j;
        o[j] = fmaxf(acc[i][j] + b1[c], 0.f);
      }
      *(float4*)&hmid[(size_t)gr * 256 + c0 + (tx << 3)] = make_float4(o[0], o[1], o[2], o[3]);
      *(float4*)&hmid[(size_t)gr * 256 + c0 + (tx << 3) + 4] = make_float4(o[4], o[5], o[6], o[7]);
    }
  }
}

// ------------- FFN2: hfin = affine1(h) + hmid@W2 + b2; accumulate BN2 stats
__global__ __launch_bounds__(256)
void ffn2(const float* __restrict__ W2, const float* __restrict__ b2, float* __restrict__ ws) {
  __shared__ float As[32][68];
  __shared__ float Bs[32][128];
  const float* hmid = ws + HMID_OFF;
  const float* h = ws + H_OFF;
  const float* a1 = ws + ST_OFF + 512;
  const float* bb1 = ws + ST_OFF + 640;
  float* hfin = ws + HFIN_OFF;
  float* st = ws + ST_OFF;
  const int tid = threadIdx.x;
  const int tx = tid & 15, ty = tid >> 4;
  const int row0 = blockIdx.x * 64;

  float acc[4][8];
#pragma unroll
  for (int i = 0; i < 4; ++i)
#pragma unroll
    for (int j = 0; j < 8; ++j) acc[i][j] = 0.f;

  for (int k0 = 0; k0 < 256; k0 += 32) {
#pragma unroll
    for (int j = 0; j < 2; ++j) {
      int s = tid + 256 * j;
      int r = s >> 3, kg = (s & 7) << 2;
      int gr = row0 + r;
      float4 v = make_float4(0.f, 0.f, 0.f, 0.f);
      if (gr < NN) v = *(const float4*)&hmid[(size_t)gr * 256 + k0 + kg];
      As[kg + 0][r] = v.x; As[kg + 1][r] = v.y; As[kg + 2][r] = v.z; As[kg + 3][r] = v.w;
    }
#pragma unroll
    for (int j = 0; j < 4; ++j) {
      int s = tid + 256 * j;
      int kk = s >> 5, cg = (s & 31) << 2;
      *(float4*)&Bs[kk][cg] = *(const float4*)&W2[(size_t)(k0 + kk) * 128 + cg];
    }
    __syncthreads();
#pragma unroll
    for (int k = 0; k < 32; ++k) {
      float4 a4 = *(float4*)&As[k][ty << 2];
      float4 b4a = *(float4*)&Bs[k][tx << 3];
      float4 b4b = *(float4*)&Bs[k][(tx << 3) + 4];
      float av[4] = {a4.x, a4.y, a4.z, a4.w};
      float bv[8] = {b4a.x, b4a.y, b4a.z, b4a.w, b4b.x, b4b.y, b4b.z, b4b.w};
#pragma unroll
      for (int i = 0; i < 4; ++i)
#pragma unroll
        for (int j = 0; j < 8; ++j) acc[i][j] = fmaf(av[i], bv[j], acc[i][j]);
    }
    __syncthreads();
  }

  float psum[8] = {0, 0, 0, 0, 0, 0, 0, 0}, psq[8] = {0, 0, 0, 0, 0, 0, 0, 0};
#pragma unroll
  for (int i = 0; i < 4; ++i) {
    int gr = row0 + (ty << 2) + i;
    if (gr < NN) {
      float o[8];
#pragma unroll
      for (int j = 0; j < 8; ++j) {
        int c = (tx << 3) + j;
        float hn = h[(size_t)gr * 128 + c] * a1[c] + bb1[c];
        float v = acc[i][j] + b2[c] + hn;
        o[j] = v;
        psum[j] += v;
        psq[j] += v * v;
      }
      *(float4*)&hfin[(size_t)gr * 128 + (tx << 3)] = make_float4(o[0], o[1], o[2], o[3]);
      *(float4*)&hfin[(size_t)gr * 128 + (tx << 3) + 4] = make_float4(o[4], o[5], o[6], o[7]);
    }
  }
  float* red = &Bs[0][0];  // 4096 floats, free after last sync
#pragma unroll
  for (int j = 0; j < 8; ++j) {
    red[ty * 128 + (tx << 3) + j] = psum[j];
    red[2048 + ty * 128 + (tx << 3) + j] = psq[j];
  }
  __syncthreads();
  if (tid < 128) {
    float ssum = 0.f, ssq = 0.f;
#pragma unroll
    for (int t = 0; t < 16; ++t) {
      ssum += red[t * 128 + tid];
      ssq += red[2048 + t * 128 + tid];
    }
    atomicAdd(&st[256 + tid], ssum);
    atomicAdd(&st[384 + tid], ssq);
  }
}

// --------------------------- final BN2 apply
__global__ __launch_bounds__(256)
void bn2_apply(const float* __restrict__ ws, float* __restrict__ out) {
  const float* hfin = ws + HFIN_OFF;
  const float* st = ws + ST_OFF;
  const int total4 = NN * 128 / 4;
  for (int i = blockIdx.x * blockDim.x + threadIdx.x; i < total4; i += gridDim.x * blockDim.x) {
    int cg = (i & 31) << 2;
    float4 v = *(const float4*)&hfin[(size_t)i * 4];
    float4 a = *(const float4*)&st[768 + cg];
    float4 b = *(const float4*)&st[896 + cg];
    float4 o;
    o.x = v.x * a.x + b.x; o.y = v.y * a.y + b.y;
    o.z = v.z * a.z + b.z; o.w = v.w * a.w + b.w;
    *(float4*)&out[(size_t)i * 4] = o;
  }
}

extern "C" void kernel_launch(void* const* d_in, const int* in_sizes, int n_in,
                              void* d_out, int out_size, void* d_ws, size_t ws_size,
                              hipStream_t stream) {
  const float* x = (const float*)d_in[0];
  const float* edge_attr = (const float*)d_in[1];
  const void* eidx = d_in[2];
  const float* Wq = (const float*)d_in[3];
  const float* Wk = (const float*)d_in[4];
  const float* We = (const float*)d_in[5];
  const float* Wv = (const float*)d_in[6];
  const float* bn1_g = (const float*)d_in[7];
  const float* bn1_b = (const float*)d_in[8];
  const float* W1 = (const float*)d_in[9];
  const float* b1 = (const float*)d_in[10];
  const float* W2 = (const float*)d_in[11];
  const float* b2 = (const float*)d_in[12];
  const float* bn2_g = (const float*)d_in[13];
  const float* bn2_b = (const float*)d_in[14];
  float* ws = (float*)d_ws;
  float* out = (float*)d_out;
  float* score = out;   // d_out doubles as score scratch (4.8M <= 6.4M floats)

  // zero cnt+cursor (contiguous 100k ints) and BN stat accumulators
  hipMemsetAsync(ws + CNT_OFF, 0, 100000 * sizeof(int), stream);
  hipMemsetAsync(ws + ST_OFF, 0, 512 * sizeof(float), stream);

  dim3 b256(256);
  detect_eidx<<<1, 256, 0, stream>>>((const int*)eidx, ws);
  count_deg<<<dim3(2344), b256, 0, stream>>>(eidx, ws);
  scan_deg<<<1, 1024, 0, stream>>>(ws);
  fill_csr<<<dim3(2344), b256, 0, stream>>>(eidx, ws);
  proj_qkv<<<dim3(782, 3), b256, 0, stream>>>(x, Wq, Wk, Wv, ws);
  edge_score<<<dim3(9375), b256, 0, stream>>>(edge_attr, eidx, We, ws, score);
  aggregate<<<dim3(512), b256, 0, stream>>>(x, score, ws);
  bn_finalize<<<1, 128, 0, stream>>>(bn1_g, bn1_b, ws, 0, 512);
  ffn1<<<dim3(782, 2), b256, 0, stream>>>(W1, b1, ws);
  ffn2<<<dim3(782), b256, 0, stream>>>(W2, b2, ws);
  bn_finalize<<<1, 128, 0, stream>>>(bn2_g, bn2_b, ws, 256, 768);
  bn2_apply<<<dim3(2048), b256, 0, stream>>>(ws, out);
}